// Round 3
// baseline (1069.941 us; speedup 1.0000x reference)
//
#include <hip/hip_runtime.h>
#include <hip/hip_bf16.h>

#define N_PTS 8192
#define NSAMP 1024
#define NGRP  32

typedef __attribute__((ext_vector_type(8))) short bf16x8;   // MFMA A/B frag
typedef __attribute__((ext_vector_type(4))) float f32x4;    // MFMA C/D frag
typedef __attribute__((ext_vector_type(2))) float f32x2;    // packed fp32 pair

static __device__ inline unsigned short f2bf(float f) {
  __hip_bfloat16 h = __float2bfloat16(f);   // RTNE
  return __builtin_bit_cast(unsigned short, h);
}

// DPP max step: invalid lanes keep 'old' (=r), identity for max.
#define DPP_MAXSTEP(r, ctrl)                                                  \
  r = fmaxf(r, __int_as_float(__builtin_amdgcn_update_dpp(                    \
          __float_as_int(r), __float_as_int(r), (ctrl), 0xf, 0xf, false)))

// 4-slot cross-wave argmax from LDS (strict > keeps lowest wave on ties).
#define FINAL4(P, V, F) do {                                                  \
    const uint4* pp_ = (const uint4*)&(P)[0];                                 \
    uint4 p0_ = pp_[0], p1_ = pp_[1];                                         \
    V = __uint_as_float(p0_.x); F = p0_.y;                                    \
    float q_;                                                                 \
    q_ = __uint_as_float(p0_.z); if (q_ > V) { V = q_; F = p0_.w; }           \
    q_ = __uint_as_float(p1_.x); if (q_ > V) { V = q_; F = p1_.y; }           \
    q_ = __uint_as_float(p1_.z); if (q_ > V) { V = q_; F = p1_.w; }           \
  } while (0)

// ---------------------------------------------------------------------------
// Kernel 1: farthest point sampling — R13.
// R12 post-mortem: issue cut landed (−214cy/iter by VALUBusy) but wall only
// fell 91cy -> kernel is latency/serialization-bound: ~716cy issue + ~1200cy
// serial (DPP chain, ballot, barrier, 2x dependent LDS round trips; lockstep
// waves stall at the same point so 2 waves/SIMD hide nothing).
// R13 shrinks the serial machine: 256 threads x 32 pts (was 512 x 16):
//   - 1 wave/SIMD: per-wave overhead paid half as often; issue ~560cy/SIMD
//   - cross-wave reduce: 4 slots, one 32B read, FINAL chain 3 steps
//   - barrier: 4 participants, less skew
// Bit-exact: lane order == index order, lowest-r / lowest-lane / lowest-wave
// tie-break chain preserved; per-point rounding untouched:
//   d = fma(dz,dz, fma(dy,dy, dx*dx))          (bit-exact, DO NOT TOUCH)
// ---------------------------------------------------------------------------
__global__
__attribute__((amdgpu_flat_work_group_size(256, 256)))
__attribute__((amdgpu_waves_per_eu(1, 1)))
void fps_kernel(
    const float* __restrict__ xyz, float* __restrict__ out_sampled)
{
  #pragma clang fp contract(off)
  const int b = blockIdx.x;
  const int t = threadIdx.x;
  const float* bx = xyz + (size_t)b * N_PTS * 3;

  // load 32 points/thread (96 floats = 24 float4), de-interleave, pack pairs
  f32x2 px2[16], py2[16], pz2[16], ds2[16];
  {
    float x[32], y[32], z[32];
    const float4* src = (const float4*)(bx + t * 96);
    #pragma unroll
    for (int g = 0; g < 8; ++g) {       // 4 points per 3 float4s
      float4 v0 = src[g * 3 + 0], v1 = src[g * 3 + 1], v2 = src[g * 3 + 2];
      x[4*g+0]=v0.x; y[4*g+0]=v0.y; z[4*g+0]=v0.z;
      x[4*g+1]=v0.w; y[4*g+1]=v1.x; z[4*g+1]=v1.y;
      x[4*g+2]=v1.z; y[4*g+2]=v1.w; z[4*g+2]=v2.x;
      x[4*g+3]=v2.y; y[4*g+3]=v2.z; z[4*g+3]=v2.w;
    }
    #pragma unroll
    for (int j = 0; j < 16; ++j) {
      px2[j] = (f32x2){x[2*j], x[2*j+1]};
      py2[j] = (f32x2){y[2*j], y[2*j+1]};
      pz2[j] = (f32x2){z[2*j], z[2*j+1]};
      ds2[j] = (f32x2){10000000000.0f, 10000000000.0f};
    }
  }

  __shared__ float lds_p[N_PTS * 3];    // full point table (96 KB): centroid
  __shared__ float out_lds[NSAMP * 3];  // centroids, flushed at end
  __shared__ __align__(16) uint2 part[2][4];  // ping-pong (value bits, index)

  // one-time coalesced stage of the point table (visible at first barrier)
  for (int i = t; i < N_PTS * 3; i += 256) lds_p[i] = bx[i];

  const int lane = t & 63;
  const int wv   = t >> 6;

  float cx = bx[0], cy = bx[1], cz = bx[2];  // initial centroid = point 0

  for (int it = 0; it < NSAMP; ++it) {
    if (t == 0) {
      out_lds[it * 3 + 0] = cx;
      out_lds[it * 3 + 1] = cy;
      out_lds[it * 3 + 2] = cz;
    }

    const f32x2 c2x = (f32x2){cx, cx};
    const f32x2 c2y = (f32x2){cy, cy};
    const f32x2 c2z = (f32x2){cz, cz};
    f32x2 bv2 = (f32x2){-1.0f, -1.0f};
    #pragma unroll
    for (int j = 0; j < 16; ++j) {
      f32x2 dx = px2[j] - c2x;
      f32x2 dy = py2[j] - c2y;
      f32x2 dz = pz2[j] - c2z;
      f32x2 d  = __builtin_elementwise_fma(
          dz, dz, __builtin_elementwise_fma(dy, dy, dx * dx));  // scan-fused
      f32x2 nd = __builtin_elementwise_min(ds2[j], d);
      ds2[j] = nd;
      bv2 = __builtin_elementwise_max(bv2, nd);
    }
    float bv = fmaxf(bv2.x, bv2.y);   // min/max reassociation is exact

    int bi = t * 32 + 31;
    #pragma unroll
    for (int r = 30; r >= 0; --r) {
      float dr = (r & 1) ? ds2[r >> 1].y : ds2[r >> 1].x;
      bi = (dr == bv) ? (t * 32 + r) : bi;
    }

    float rmax = bv;
    DPP_MAXSTEP(rmax, 0x111);  // row_shr:1
    DPP_MAXSTEP(rmax, 0x112);  // row_shr:2
    DPP_MAXSTEP(rmax, 0x114);  // row_shr:4
    DPP_MAXSTEP(rmax, 0x118);  // row_shr:8
    DPP_MAXSTEP(rmax, 0x142);  // row_bcast:15
    DPP_MAXSTEP(rmax, 0x143);  // row_bcast:31
    float vmax = __int_as_float(
        __builtin_amdgcn_readlane(__float_as_int(rmax), 63));

    unsigned long long m = __ballot(bv == vmax);
    int L = __ffsll((long long)m) - 1;
    int widx = __builtin_amdgcn_readlane(bi, L);

    const int slot = it & 1;
    if (lane == 0) part[slot][wv] = make_uint2(__float_as_uint(vmax), (unsigned)widx);
    __syncthreads();   // the ONLY barrier; ping-pong makes it WAR-safe

    float v; unsigned f;
    FINAL4(part[slot], v, f);

    cx = lds_p[f * 3 + 0];   // broadcast ds_read (beats global L2 ~200cy)
    cy = lds_p[f * 3 + 1];
    cz = lds_p[f * 3 + 2];
  }

  __syncthreads();
  float* ob = out_sampled + (size_t)b * NSAMP * 3;
  for (int i = t; i < NSAMP * 3; i += 256) ob[i] = out_lds[i];
}

// ---------------------------------------------------------------------------
// Kernel 2: query_ball_point — unchanged (bit-exact, DO NOT TOUCH).
// ---------------------------------------------------------------------------
__global__ __launch_bounds__(256) void ball_kernel(
    const float* __restrict__ xyz, const float* __restrict__ sampled,
    int* __restrict__ gidx)
{
  #pragma clang fp contract(off)
  const float R2 = (float)(0.2 * 0.2);
  int gt = blockIdx.x * 256 + threadIdx.x;
  int w = gt >> 6;
  int lane = gt & 63;
  const int b = w >> 10;
  const float* cp = sampled + (size_t)w * 3;
  float cx = cp[0], cy = cp[1], cz = cp[2];
  float na = ((cx * cx) + (cy * cy)) + (cz * cz);   // eager: plain adds
  const float* bx = xyz + (size_t)b * N_PTS * 3;
  int* out = gidx + (size_t)w * NGRP;

  int cnt = 0;
  int first = 0;
  for (int base = 0; base < N_PTS && cnt < NGRP; base += 64) {
    int p = base + lane;
    float x = bx[p * 3 + 0];
    float y = bx[p * 3 + 1];
    float z = bx[p * 3 + 2];
    float nb  = ((x * x) + (y * y)) + (z * z);      // eager: plain adds
    float dot = fmaf(cz, z, fmaf(cy, y, cx * x));   // Eigen fma chain
    float sq  = (na + nb) - (2.0f * dot);
    bool inr = !(sq > R2);
    unsigned long long m = __ballot(inr);
    if (cnt == 0 && m != 0ull) first = base + (__ffsll(m) - 1);
    int before = __popcll(m & ((1ull << lane) - 1ull));
    int pos = cnt + before;
    if (inr && pos < NGRP) out[pos] = p;
    cnt += __popcll(m);
  }
  if (cnt < NGRP) {
    int q = cnt + lane;
    if (q < NGRP) out[q] = first;
  }
}

// ---------------------------------------------------------------------------
// Kernel 2.5: weight prep — pack W1/W2/W3 into fragment-ordered bf16 records.
// Record (nt, ks) holds the B-fragment for one 16-col tile / one K-step:
//   record[lane][j] = W[k = 32ks + (lane>>4)*8 + j][n = 16nt + (lane&15)]
// (zero-padded k >= K). 1KB/record, lane*16B consecutive -> coalesced loads.
// Layers: L1 4nt x 3ks = 12 recs, L2 8x2 = 16, L3 16x4 = 64. Total 92KB.
// ---------------------------------------------------------------------------
__global__ __launch_bounds__(256) void prep_w_kernel(
    const float* __restrict__ W1, const float* __restrict__ W2,
    const float* __restrict__ W3, unsigned short* __restrict__ wf1,
    unsigned short* __restrict__ wf2, unsigned short* __restrict__ wf3)
{
  int tid = blockIdx.x * 256 + threadIdx.x;
  int rec = tid >> 6, lane = tid & 63;
  if (rec >= 92) return;
  const float* W; unsigned short* dst; int N, K, ksteps, rl;
  if (rec < 12)      { W = W1; dst = wf1; N = 64;  K = 67;  ksteps = 3; rl = rec; }
  else if (rec < 28) { W = W2; dst = wf2; N = 128; K = 64;  ksteps = 2; rl = rec - 12; }
  else               { W = W3; dst = wf3; N = 256; K = 128; ksteps = 4; rl = rec - 28; }
  int nt = rl / ksteps, ks = rl - nt * ksteps;
  int n  = nt * 16 + (lane & 15);
  int kb = ks * 32 + (lane >> 4) * 8;
  unsigned short v[8] __attribute__((aligned(16)));
  #pragma unroll
  for (int j = 0; j < 8; ++j) {
    int k = kb + j;
    v[j] = f2bf((k < K) ? W[k * N + n] : 0.0f);
  }
  *(uint4*)(dst + ((size_t)rl * 64 + lane) * 8) = *(const uint4*)v;
}

// ---------------------------------------------------------------------------
// Kernel 3: gather + MLP via bf16 MFMA (fp32 accumulate) + max-pool.
// One 256-thread block (4 waves) per centroid.
// Frag layouts (gfx950, HW-verified per guide):
//   A[m=lane&15][k=(lane>>4)*8+j]   B[n=lane&15][k=(lane>>4)*8+j]
//   C/D: col=lane&15, row=(lane>>4)*4+reg
// Activations in bf16 LDS tiles, row stride K+8 (breaks 128B bank pathology).
// B-frags load straight from fragment-ordered global records (L2-hot).
// Accuracy: bf16 operand rounding -> out err ~2-5e-3 << 2e-2 threshold.
// ---------------------------------------------------------------------------
__global__ __launch_bounds__(256, 4) void mlp_mfma_kernel(
    const float* __restrict__ xyz, const float* __restrict__ fea,
    const float* __restrict__ sampled, const int* __restrict__ gidx,
    const unsigned short* __restrict__ wf1, const unsigned short* __restrict__ wf2,
    const unsigned short* __restrict__ wf3, const float* __restrict__ b1,
    const float* __restrict__ b2, const float* __restrict__ b3,
    float* __restrict__ out)
{
  __shared__ __align__(16) unsigned short fT[32][104];  // feats bf16, K=96 pad
  __shared__ __align__(16) unsigned short h1[32][72];   // K=64 (+8 bank pad)
  __shared__ __align__(16) unsigned short h2[32][136];  // K=128 (+8 bank pad)
  __shared__ float pmax[8][256];
  __shared__ int   sidx[32];
  __shared__ float sc[4];

  const int bs = blockIdx.x;
  const int b  = bs >> 10;
  const int t  = threadIdx.x;
  const int w    = t >> 6;
  const int lane = t & 63;
  const int quad = lane >> 4;
  const int ncol = lane & 15;

  if (t < 32) sidx[t] = gidx[(size_t)bs * 32 + t];
  if (t < 3)  sc[t] = sampled[(size_t)bs * 3 + t];
  __syncthreads();

  // gather: rel(3) ++ fea(64) -> bf16 fT[pt][c], zero pad c in [67,96)
  {
    const int pt = t >> 3, c0 = t & 7;
    const int p = sidx[pt];
    const float* xp = xyz + ((size_t)b * N_PTS + p) * 3;
    const float* fp = fea + ((size_t)b * N_PTS + p) * 64;
    for (int c = c0; c < 96; c += 8) {
      float v = (c < 3) ? (xp[c] - sc[c]) : (c < 67 ? fp[c - 3] : 0.0f);
      fT[pt][c] = f2bf(v);
    }
  }
  __syncthreads();

  // layer 1: out [32 x 64]. 8 tiles (2m x 4n), 2/wave; K: 3 steps.
  #pragma unroll
  for (int q2 = 0; q2 < 2; ++q2) {
    const int tid = w * 2 + q2, mt = tid & 1, nt = tid >> 1;
    float bb = b1[nt * 16 + ncol];
    f32x4 acc = {bb, bb, bb, bb};
    #pragma unroll
    for (int ks = 0; ks < 3; ++ks) {
      bf16x8 a = *(const bf16x8*)&fT[mt * 16 + ncol][ks * 32 + quad * 8];
      bf16x8 bf = *(const bf16x8*)(wf1 + ((size_t)(nt * 3 + ks) * 64 + lane) * 8);
      acc = __builtin_amdgcn_mfma_f32_16x16x32_bf16(a, bf, acc, 0, 0, 0);
    }
    #pragma unroll
    for (int r = 0; r < 4; ++r)
      h1[mt * 16 + quad * 4 + r][nt * 16 + ncol] = f2bf(fmaxf(acc[r], 0.0f));
  }
  __syncthreads();

  // layer 2: out [32 x 128]. 16 tiles (2m x 8n), 4/wave; K: 2 steps.
  #pragma unroll
  for (int q2 = 0; q2 < 4; ++q2) {
    const int tid = w * 4 + q2, mt = tid & 1, nt = tid >> 1;
    float bb = b2[nt * 16 + ncol];
    f32x4 acc = {bb, bb, bb, bb};
    #pragma unroll
    for (int ks = 0; ks < 2; ++ks) {
      bf16x8 a = *(const bf16x8*)&h1[mt * 16 + ncol][ks * 32 + quad * 8];
      bf16x8 bf = *(const bf16x8*)(wf2 + ((size_t)(nt * 2 + ks) * 64 + lane) * 8);
      acc = __builtin_amdgcn_mfma_f32_16x16x32_bf16(a, bf, acc, 0, 0, 0);
    }
    #pragma unroll
    for (int r = 0; r < 4; ++r)
      h2[mt * 16 + quad * 4 + r][nt * 16 + ncol] = f2bf(fmaxf(acc[r], 0.0f));
  }
  __syncthreads();

  // layer 3 + pool: out [32 x 256]. 32 tiles (2m x 16n), 8/wave; K: 4 steps.
  #pragma unroll
  for (int q2 = 0; q2 < 8; ++q2) {
    const int tid = w * 8 + q2, mt = tid & 1, nt = tid >> 1;
    float bb = b3[nt * 16 + ncol];
    f32x4 acc = {bb, bb, bb, bb};
    #pragma unroll
    for (int ks = 0; ks < 4; ++ks) {
      bf16x8 a = *(const bf16x8*)&h2[mt * 16 + ncol][ks * 32 + quad * 8];
      bf16x8 bf = *(const bf16x8*)(wf3 + ((size_t)(nt * 4 + ks) * 64 + lane) * 8);
      acc = __builtin_amdgcn_mfma_f32_16x16x32_bf16(a, bf, acc, 0, 0, 0);
    }
    float mx = fmaxf(fmaxf(acc[0], acc[1]), fmaxf(acc[2], acc[3]));
    pmax[mt * 4 + quad][nt * 16 + ncol] = mx;   // partial over 4 rows
  }
  __syncthreads();

  {
    float v = pmax[0][t];
    #pragma unroll
    for (int s = 1; s < 8; ++s) v = fmaxf(v, pmax[s][t]);
    out[(size_t)bs * 256 + t] = fmaxf(v, 0.0f);   // relu(max) == max(relu)
  }
}

// ---------------------------------------------------------------------------
extern "C" void kernel_launch(void* const* d_in, const int* in_sizes, int n_in,
                              void* d_out, int out_size, void* d_ws, size_t ws_size,
                              hipStream_t stream) {
  const float* xyz = (const float*)d_in[0];
  const float* fea = (const float*)d_in[1];
  const float* W1  = (const float*)d_in[2];
  const float* b1  = (const float*)d_in[3];
  const float* W2  = (const float*)d_in[4];
  const float* b2  = (const float*)d_in[5];
  const float* W3  = (const float*)d_in[6];
  const float* b3  = (const float*)d_in[7];

  float* outp    = (float*)d_out;
  float* sampled = outp;                    // output 0: (16,1024,3)
  float* mlp_out = outp + 16 * 1024 * 3;    // output 1: (16,1024,256)
  int*   gidx    = (int*)d_ws;              // 2 MB
  unsigned short* wf1 = (unsigned short*)((char*)d_ws + (2u << 20));
  unsigned short* wf2 = wf1 + (size_t)12 * 64 * 8;   // 12 KB after wf1
  unsigned short* wf3 = wf2 + (size_t)16 * 64 * 8;   // 16 KB after wf2

  fps_kernel<<<16, 256, 0, stream>>>(xyz, sampled);
  prep_w_kernel<<<23, 256, 0, stream>>>(W1, W2, W3, wf1, wf2, wf3);
  ball_kernel<<<4096, 256, 0, stream>>>(xyz, sampled, gidx);
  mlp_mfma_kernel<<<16384, 256, 0, stream>>>(xyz, fea, sampled, gidx,
                                             wf1, wf2, wf3, b1, b2, b3, mlp_out);
}

// Round 4
// 1034.000 us; speedup vs baseline: 1.0348x; 1.0348x over previous
//
#include <hip/hip_runtime.h>
#include <hip/hip_bf16.h>

#define N_PTS 8192
#define NSAMP 1024
#define NGRP  32

typedef __attribute__((ext_vector_type(8))) short bf16x8;   // MFMA A/B frag
typedef __attribute__((ext_vector_type(4))) float f32x4;    // MFMA C/D frag
typedef __attribute__((ext_vector_type(2))) float f32x2;    // packed fp32 pair

static __device__ inline unsigned short f2bf(float f) {
  __hip_bfloat16 h = __float2bfloat16(f);   // RTNE
  return __builtin_bit_cast(unsigned short, h);
}

// DPP max step: invalid lanes keep 'old' (=r), identity for max.
#define DPP_MAXSTEP(r, ctrl)                                                  \
  r = fmaxf(r, __int_as_float(__builtin_amdgcn_update_dpp(                    \
          __float_as_int(r), __float_as_int(r), (ctrl), 0xf, 0xf, false)))

// 8-slot cross-wave argmax from LDS (strict > keeps lowest wave on ties).
#define FINAL8(P, V, F) do {                                                  \
    const uint4* pp_ = (const uint4*)&(P)[0];                                 \
    uint4 p0_ = pp_[0], p1_ = pp_[1], p2_ = pp_[2], p3_ = pp_[3];             \
    V = __uint_as_float(p0_.x); F = p0_.y;                                    \
    float q_;                                                                 \
    q_ = __uint_as_float(p0_.z); if (q_ > V) { V = q_; F = p0_.w; }           \
    q_ = __uint_as_float(p1_.x); if (q_ > V) { V = q_; F = p1_.y; }           \
    q_ = __uint_as_float(p1_.z); if (q_ > V) { V = q_; F = p1_.w; }           \
    q_ = __uint_as_float(p2_.x); if (q_ > V) { V = q_; F = p2_.y; }           \
    q_ = __uint_as_float(p2_.z); if (q_ > V) { V = q_; F = p2_.w; }           \
    q_ = __uint_as_float(p3_.x); if (q_ > V) { V = q_; F = p3_.y; }           \
    q_ = __uint_as_float(p3_.z); if (q_ > V) { V = q_; F = p3_.w; }           \
  } while (0)

static __device__ inline void load16(const float* __restrict__ bx, int t,
                                     float px[16], float py[16], float pz[16]) {
  const float4* src = (const float4*)(bx + t * 48);
  float4 v0 = src[0], v1 = src[1], v2 = src[2];
  float4 v3 = src[3], v4 = src[4], v5 = src[5];
  float4 v6 = src[6], v7 = src[7], v8 = src[8];
  float4 v9 = src[9], v10 = src[10], v11 = src[11];
  px[ 0]=v0.x; py[ 0]=v0.y; pz[ 0]=v0.z;
  px[ 1]=v0.w; py[ 1]=v1.x; pz[ 1]=v1.y;
  px[ 2]=v1.z; py[ 2]=v1.w; pz[ 2]=v2.x;
  px[ 3]=v2.y; py[ 3]=v2.z; pz[ 3]=v2.w;
  px[ 4]=v3.x; py[ 4]=v3.y; pz[ 4]=v3.z;
  px[ 5]=v3.w; py[ 5]=v4.x; pz[ 5]=v4.y;
  px[ 6]=v4.z; py[ 6]=v4.w; pz[ 6]=v5.x;
  px[ 7]=v5.y; py[ 7]=v5.z; pz[ 7]=v5.w;
  px[ 8]=v6.x; py[ 8]=v6.y; pz[ 8]=v6.z;
  px[ 9]=v6.w; py[ 9]=v7.x; pz[ 9]=v7.y;
  px[10]=v7.z; py[10]=v7.w; pz[10]=v8.x;
  px[11]=v8.y; py[11]=v8.z; pz[11]=v8.w;
  px[12]=v9.x; py[12]=v9.y; pz[12]=v9.z;
  px[13]=v9.w; py[13]=v10.x; pz[13]=v10.y;
  px[14]=v10.z; py[14]=v10.w; pz[14]=v11.x;
  px[15]=v11.y; py[15]=v11.z; pz[15]=v11.w;
}

// ---------------------------------------------------------------------------
// Kernel 1: farthest point sampling — R12 config (empirical optimum, 821us).
// R11-R13 post-mortems: wall pinned at ~1900-2000 cy/iter across 3 structural
// variants; every removed issue-cycle becomes idle (serial chain ~1400cy:
// dist dep-chain -> DPP reduce -> ballot -> LDS write -> barrier drain ->
// LDS read -> select -> dependent centroid ds_read). 512thr x 16pts packed
// + LDS point table is the floor of this structure. DO NOT TINKER.
//   d = fma(dz,dz, fma(dy,dy, dx*dx))          (bit-exact, DO NOT TOUCH)
// argmax ties -> lowest index.
// ---------------------------------------------------------------------------
__global__
__attribute__((amdgpu_flat_work_group_size(512, 512)))
__attribute__((amdgpu_waves_per_eu(2, 2)))
void fps_kernel(
    const float* __restrict__ xyz, float* __restrict__ out_sampled)
{
  #pragma clang fp contract(off)
  const int b = blockIdx.x;
  const int t = threadIdx.x;
  const float* bx = xyz + (size_t)b * N_PTS * 3;

  float px[16], py[16], pz[16];
  load16(bx, t, px, py, pz);

  f32x2 px2[8], py2[8], pz2[8], ds2[8];
  #pragma unroll
  for (int j = 0; j < 8; ++j) {
    px2[j] = (f32x2){px[2*j], px[2*j+1]};
    py2[j] = (f32x2){py[2*j], py[2*j+1]};
    pz2[j] = (f32x2){pz[2*j], pz[2*j+1]};
    ds2[j] = (f32x2){10000000000.0f, 10000000000.0f};
  }

  __shared__ float lds_p[N_PTS * 3];    // full point table (96 KB): centroid
  __shared__ float out_lds[NSAMP * 3];  // centroids, flushed at end
  __shared__ __align__(16) uint2 part[2][8];  // ping-pong (value bits, index)

  // one-time coalesced stage of the point table (visible at first barrier)
  for (int i = t; i < N_PTS * 3; i += 512) lds_p[i] = bx[i];

  const int lane = t & 63;
  const int wv   = t >> 6;

  float cx = bx[0], cy = bx[1], cz = bx[2];  // initial centroid = point 0

  for (int it = 0; it < NSAMP; ++it) {
    if (t == 0) {
      out_lds[it * 3 + 0] = cx;
      out_lds[it * 3 + 1] = cy;
      out_lds[it * 3 + 2] = cz;
    }

    const f32x2 c2x = (f32x2){cx, cx};
    const f32x2 c2y = (f32x2){cy, cy};
    const f32x2 c2z = (f32x2){cz, cz};
    f32x2 bv2 = (f32x2){-1.0f, -1.0f};
    #pragma unroll
    for (int j = 0; j < 8; ++j) {
      f32x2 dx = px2[j] - c2x;
      f32x2 dy = py2[j] - c2y;
      f32x2 dz = pz2[j] - c2z;
      f32x2 d  = __builtin_elementwise_fma(
          dz, dz, __builtin_elementwise_fma(dy, dy, dx * dx));  // scan-fused
      f32x2 nd = __builtin_elementwise_min(ds2[j], d);
      ds2[j] = nd;
      bv2 = __builtin_elementwise_max(bv2, nd);
    }
    float bv = fmaxf(bv2.x, bv2.y);   // min/max reassociation is exact

    int bi = t * 16 + 15;
    #pragma unroll
    for (int r = 14; r >= 0; --r) {
      float dr = (r & 1) ? ds2[r >> 1].y : ds2[r >> 1].x;
      bi = (dr == bv) ? (t * 16 + r) : bi;
    }

    float rmax = bv;
    DPP_MAXSTEP(rmax, 0x111);  // row_shr:1
    DPP_MAXSTEP(rmax, 0x112);  // row_shr:2
    DPP_MAXSTEP(rmax, 0x114);  // row_shr:4
    DPP_MAXSTEP(rmax, 0x118);  // row_shr:8
    DPP_MAXSTEP(rmax, 0x142);  // row_bcast:15
    DPP_MAXSTEP(rmax, 0x143);  // row_bcast:31
    float vmax = __int_as_float(
        __builtin_amdgcn_readlane(__float_as_int(rmax), 63));

    unsigned long long m = __ballot(bv == vmax);
    int L = __ffsll((long long)m) - 1;
    int widx = __builtin_amdgcn_readlane(bi, L);

    const int slot = it & 1;
    if (lane == 0) part[slot][wv] = make_uint2(__float_as_uint(vmax), (unsigned)widx);
    __syncthreads();   // the ONLY barrier; ping-pong makes it WAR-safe

    float v; unsigned f;
    FINAL8(part[slot], v, f);

    cx = lds_p[f * 3 + 0];   // broadcast ds_read (beats global L2 ~200cy)
    cy = lds_p[f * 3 + 1];
    cz = lds_p[f * 3 + 2];
  }

  __syncthreads();
  float* ob = out_sampled + (size_t)b * NSAMP * 3;
  for (int i = t; i < NSAMP * 3; i += 512) ob[i] = out_lds[i];
}

// ---------------------------------------------------------------------------
// Kernel 2: query_ball_point — unchanged (bit-exact, DO NOT TOUCH).
// ---------------------------------------------------------------------------
__global__ __launch_bounds__(256) void ball_kernel(
    const float* __restrict__ xyz, const float* __restrict__ sampled,
    int* __restrict__ gidx)
{
  #pragma clang fp contract(off)
  const float R2 = (float)(0.2 * 0.2);
  int gt = blockIdx.x * 256 + threadIdx.x;
  int w = gt >> 6;
  int lane = gt & 63;
  const int b = w >> 10;
  const float* cp = sampled + (size_t)w * 3;
  float cx = cp[0], cy = cp[1], cz = cp[2];
  float na = ((cx * cx) + (cy * cy)) + (cz * cz);   // eager: plain adds
  const float* bx = xyz + (size_t)b * N_PTS * 3;
  int* out = gidx + (size_t)w * NGRP;

  int cnt = 0;
  int first = 0;
  for (int base = 0; base < N_PTS && cnt < NGRP; base += 64) {
    int p = base + lane;
    float x = bx[p * 3 + 0];
    float y = bx[p * 3 + 1];
    float z = bx[p * 3 + 2];
    float nb  = ((x * x) + (y * y)) + (z * z);      // eager: plain adds
    float dot = fmaf(cz, z, fmaf(cy, y, cx * x));   // Eigen fma chain
    float sq  = (na + nb) - (2.0f * dot);
    bool inr = !(sq > R2);
    unsigned long long m = __ballot(inr);
    if (cnt == 0 && m != 0ull) first = base + (__ffsll(m) - 1);
    int before = __popcll(m & ((1ull << lane) - 1ull));
    int pos = cnt + before;
    if (inr && pos < NGRP) out[pos] = p;
    cnt += __popcll(m);
  }
  if (cnt < NGRP) {
    int q = cnt + lane;
    if (q < NGRP) out[q] = first;
  }
}

// ---------------------------------------------------------------------------
// Kernel 2.5: weight prep — pack W1/W2/W3 into fragment-ordered bf16 records.
// Record (nt, ks) holds the B-fragment for one 16-col tile / one K-step:
//   record[lane][j] = W[k = 32ks + (lane>>4)*8 + j][n = 16nt + (lane&15)]
// (zero-padded k >= K). 1KB/record, lane*16B consecutive -> coalesced loads.
// Layers: L1 4nt x 3ks = 12 recs, L2 8x2 = 16, L3 16x4 = 64. Total 92KB.
// R14: L1 uses PERMUTED feature order (fea at k'=0..63, rel at k'=64..66,
// pad 67..95) so the mlp gather can use coalesced float4 loads. W1 rows are
// permuted to match: k'<64 -> W1 row k'+3; k'=64..66 -> W1 row k'-64.
// Same dot products; only in-MFMA summation order shifts (ulp-level).
// ---------------------------------------------------------------------------
__global__ __launch_bounds__(256) void prep_w_kernel(
    const float* __restrict__ W1, const float* __restrict__ W2,
    const float* __restrict__ W3, unsigned short* __restrict__ wf1,
    unsigned short* __restrict__ wf2, unsigned short* __restrict__ wf3)
{
  int tid = blockIdx.x * 256 + threadIdx.x;
  int rec = tid >> 6, lane = tid & 63;
  if (rec >= 92) return;
  const float* W; unsigned short* dst; int N, K, ksteps, rl; int permuted;
  if (rec < 12)      { W = W1; dst = wf1; N = 64;  K = 67;  ksteps = 3; rl = rec;     permuted = 1; }
  else if (rec < 28) { W = W2; dst = wf2; N = 128; K = 64;  ksteps = 2; rl = rec - 12; permuted = 0; }
  else               { W = W3; dst = wf3; N = 256; K = 128; ksteps = 4; rl = rec - 28; permuted = 0; }
  int nt = rl / ksteps, ks = rl - nt * ksteps;
  int n  = nt * 16 + (lane & 15);
  int kb = ks * 32 + (lane >> 4) * 8;
  unsigned short v[8] __attribute__((aligned(16)));
  #pragma unroll
  for (int j = 0; j < 8; ++j) {
    int k = kb + j;
    float val;
    if (permuted) {
      if (k < 64)      val = W[(k + 3) * N + n];   // fea weight rows
      else if (k < K)  val = W[(k - 64) * N + n];  // rel weight rows (k=64..66)
      else             val = 0.0f;
    } else {
      val = (k < K) ? W[k * N + n] : 0.0f;
    }
    v[j] = f2bf(val);
  }
  *(uint4*)(dst + ((size_t)rl * 64 + lane) * 8) = *(const uint4*)v;
}

// ---------------------------------------------------------------------------
// Kernel 3: gather + MLP via bf16 MFMA (fp32 accumulate) + max-pool.
// One 256-thread block (4 waves) per centroid.
// R14: gather vectorized. Feature order permuted (matching wf1): fea cols
// 0..63, rel cols 64..66, zero pad 67..95. Each point handled by 8 threads:
// two coalesced float4 loads (lanes c0=0..7 read fp4[c0], fp4[c0+8] ->
// 128B contiguous per point-half) -> 4x bf16 packed 8B LDS stores.
// Frag layouts (gfx950, HW-verified per guide):
//   A[m=lane&15][k=(lane>>4)*8+j]   B[n=lane&15][k=(lane>>4)*8+j]
//   C/D: col=lane&15, row=(lane>>4)*4+reg
// Activations in bf16 LDS tiles, row stride K+8 (breaks 128B bank pathology).
// B-frags load straight from fragment-ordered global records (L2-hot).
// Accuracy: bf16 operand rounding -> out err ~2-5e-3 << 2e-2 threshold.
// ---------------------------------------------------------------------------
__global__ __launch_bounds__(256, 4) void mlp_mfma_kernel(
    const float* __restrict__ xyz, const float* __restrict__ fea,
    const float* __restrict__ sampled, const int* __restrict__ gidx,
    const unsigned short* __restrict__ wf1, const unsigned short* __restrict__ wf2,
    const unsigned short* __restrict__ wf3, const float* __restrict__ b1,
    const float* __restrict__ b2, const float* __restrict__ b3,
    float* __restrict__ out)
{
  __shared__ __align__(16) unsigned short fT[32][104];  // feats bf16, K=96 pad
  __shared__ __align__(16) unsigned short h1[32][72];   // K=64 (+8 bank pad)
  __shared__ __align__(16) unsigned short h2[32][136];  // K=128 (+8 bank pad)
  __shared__ float pmax[8][256];
  __shared__ int   sidx[32];
  __shared__ float sc[4];

  const int bs = blockIdx.x;
  const int b  = bs >> 10;
  const int t  = threadIdx.x;
  const int w    = t >> 6;
  const int lane = t & 63;
  const int quad = lane >> 4;
  const int ncol = lane & 15;

  if (t < 32) sidx[t] = gidx[(size_t)bs * 32 + t];
  if (t < 3)  sc[t] = sampled[(size_t)bs * 3 + t];
  __syncthreads();

  // gather (permuted layout): fea -> cols 0..63 via 2 coalesced float4 loads
  // per thread; rel -> cols 64..66; zeros 67..95. 8 threads per point.
  {
    const int pt = t >> 3, c0 = t & 7;
    const int p = sidx[pt];
    const float4* fp4 = (const float4*)(fea + ((size_t)b * N_PTS + p) * 64);

    float4 fa = fp4[c0];
    float4 fb = fp4[c0 + 8];
    unsigned short sa[4] __attribute__((aligned(8)));
    unsigned short sb[4] __attribute__((aligned(8)));
    sa[0] = f2bf(fa.x); sa[1] = f2bf(fa.y); sa[2] = f2bf(fa.z); sa[3] = f2bf(fa.w);
    sb[0] = f2bf(fb.x); sb[1] = f2bf(fb.y); sb[2] = f2bf(fb.z); sb[3] = f2bf(fb.w);
    *(uint2*)&fT[pt][c0 * 4]      = *(const uint2*)sa;
    *(uint2*)&fT[pt][32 + c0 * 4] = *(const uint2*)sb;

    if (c0 == 0) {
      // rel(3) at cols 64..66, zero col 67; then zeros 68..71
      const float* xp = xyz + ((size_t)b * N_PTS + p) * 3;
      unsigned short sr[4] __attribute__((aligned(8)));
      sr[0] = f2bf(xp[0] - sc[0]);
      sr[1] = f2bf(xp[1] - sc[1]);
      sr[2] = f2bf(xp[2] - sc[2]);
      sr[3] = 0;
      *(uint2*)&fT[pt][64] = *(const uint2*)sr;
      *(uint2*)&fT[pt][68] = (uint2){0u, 0u};
    } else if (c0 >= 4 && c0 <= 6) {
      // zeros: c0=4 -> 72..79, c0=5 -> 80..87, c0=6 -> 88..95
      *(uint4*)&fT[pt][72 + (c0 - 4) * 8] = (uint4){0u, 0u, 0u, 0u};
    }
  }
  __syncthreads();

  // layer 1: out [32 x 64]. 8 tiles (2m x 4n), 2/wave; K: 3 steps.
  #pragma unroll
  for (int q2 = 0; q2 < 2; ++q2) {
    const int tid = w * 2 + q2, mt = tid & 1, nt = tid >> 1;
    float bb = b1[nt * 16 + ncol];
    f32x4 acc = {bb, bb, bb, bb};
    #pragma unroll
    for (int ks = 0; ks < 3; ++ks) {
      bf16x8 a = *(const bf16x8*)&fT[mt * 16 + ncol][ks * 32 + quad * 8];
      bf16x8 bf = *(const bf16x8*)(wf1 + ((size_t)(nt * 3 + ks) * 64 + lane) * 8);
      acc = __builtin_amdgcn_mfma_f32_16x16x32_bf16(a, bf, acc, 0, 0, 0);
    }
    #pragma unroll
    for (int r = 0; r < 4; ++r)
      h1[mt * 16 + quad * 4 + r][nt * 16 + ncol] = f2bf(fmaxf(acc[r], 0.0f));
  }
  __syncthreads();

  // layer 2: out [32 x 128]. 16 tiles (2m x 8n), 4/wave; K: 2 steps.
  #pragma unroll
  for (int q2 = 0; q2 < 4; ++q2) {
    const int tid = w * 4 + q2, mt = tid & 1, nt = tid >> 1;
    float bb = b2[nt * 16 + ncol];
    f32x4 acc = {bb, bb, bb, bb};
    #pragma unroll
    for (int ks = 0; ks < 2; ++ks) {
      bf16x8 a = *(const bf16x8*)&h1[mt * 16 + ncol][ks * 32 + quad * 8];
      bf16x8 bf = *(const bf16x8*)(wf2 + ((size_t)(nt * 2 + ks) * 64 + lane) * 8);
      acc = __builtin_amdgcn_mfma_f32_16x16x32_bf16(a, bf, acc, 0, 0, 0);
    }
    #pragma unroll
    for (int r = 0; r < 4; ++r)
      h2[mt * 16 + quad * 4 + r][nt * 16 + ncol] = f2bf(fmaxf(acc[r], 0.0f));
  }
  __syncthreads();

  // layer 3 + pool: out [32 x 256]. 32 tiles (2m x 16n), 8/wave; K: 4 steps.
  #pragma unroll
  for (int q2 = 0; q2 < 8; ++q2) {
    const int tid = w * 8 + q2, mt = tid & 1, nt = tid >> 1;
    float bb = b3[nt * 16 + ncol];
    f32x4 acc = {bb, bb, bb, bb};
    #pragma unroll
    for (int ks = 0; ks < 4; ++ks) {
      bf16x8 a = *(const bf16x8*)&h2[mt * 16 + ncol][ks * 32 + quad * 8];
      bf16x8 bf = *(const bf16x8*)(wf3 + ((size_t)(nt * 4 + ks) * 64 + lane) * 8);
      acc = __builtin_amdgcn_mfma_f32_16x16x32_bf16(a, bf, acc, 0, 0, 0);
    }
    float mx = fmaxf(fmaxf(acc[0], acc[1]), fmaxf(acc[2], acc[3]));
    pmax[mt * 4 + quad][nt * 16 + ncol] = mx;   // partial over 4 rows
  }
  __syncthreads();

  {
    float v = pmax[0][t];
    #pragma unroll
    for (int s = 1; s < 8; ++s) v = fmaxf(v, pmax[s][t]);
    out[(size_t)bs * 256 + t] = fmaxf(v, 0.0f);   // relu(max) == max(relu)
  }
}

// ---------------------------------------------------------------------------
extern "C" void kernel_launch(void* const* d_in, const int* in_sizes, int n_in,
                              void* d_out, int out_size, void* d_ws, size_t ws_size,
                              hipStream_t stream) {
  const float* xyz = (const float*)d_in[0];
  const float* fea = (const float*)d_in[1];
  const float* W1  = (const float*)d_in[2];
  const float* b1  = (const float*)d_in[3];
  const float* W2  = (const float*)d_in[4];
  const float* b2  = (const float*)d_in[5];
  const float* W3  = (const float*)d_in[6];
  const float* b3  = (const float*)d_in[7];

  float* outp    = (float*)d_out;
  float* sampled = outp;                    // output 0: (16,1024,3)
  float* mlp_out = outp + 16 * 1024 * 3;    // output 1: (16,1024,256)
  int*   gidx    = (int*)d_ws;              // 2 MB
  unsigned short* wf1 = (unsigned short*)((char*)d_ws + (2u << 20));
  unsigned short* wf2 = wf1 + (size_t)12 * 64 * 8;   // 12 KB after wf1
  unsigned short* wf3 = wf2 + (size_t)16 * 64 * 8;   // 16 KB after wf2

  fps_kernel<<<16, 512, 0, stream>>>(xyz, sampled);
  prep_w_kernel<<<23, 256, 0, stream>>>(W1, W2, W3, wf1, wf2, wf3);
  ball_kernel<<<4096, 256, 0, stream>>>(xyz, sampled, gidx);
  mlp_mfma_kernel<<<16384, 256, 0, stream>>>(xyz, fea, sampled, gidx,
                                             wf1, wf2, wf3, b1, b2, b3, mlp_out);
}

// Round 5
// 1014.042 us; speedup vs baseline: 1.0551x; 1.0197x over previous
//
#include <hip/hip_runtime.h>
#include <hip/hip_bf16.h>

#define N_PTS 8192
#define NSAMP 1024
#define NGRP  32

typedef __attribute__((ext_vector_type(8))) short bf16x8;   // MFMA A/B frag
typedef __attribute__((ext_vector_type(4))) float f32x4;    // MFMA C/D frag
typedef __attribute__((ext_vector_type(2))) float f32x2;    // packed fp32 pair

static __device__ inline unsigned short f2bf(float f) {
  __hip_bfloat16 h = __float2bfloat16(f);   // RTNE
  return __builtin_bit_cast(unsigned short, h);
}

// DPP max step: invalid lanes keep 'old' (=r), identity for max.
#define DPP_MAXSTEP(r, ctrl)                                                  \
  r = fmaxf(r, __int_as_float(__builtin_amdgcn_update_dpp(                    \
          __float_as_int(r), __float_as_int(r), (ctrl), 0xf, 0xf, false)))

// 8-slot cross-wave argmax from LDS (strict > keeps lowest wave on ties).
#define FINAL8(P, V, F) do {                                                  \
    const uint4* pp_ = (const uint4*)&(P)[0];                                 \
    uint4 p0_ = pp_[0], p1_ = pp_[1], p2_ = pp_[2], p3_ = pp_[3];             \
    V = __uint_as_float(p0_.x); F = p0_.y;                                    \
    float q_;                                                                 \
    q_ = __uint_as_float(p0_.z); if (q_ > V) { V = q_; F = p0_.w; }           \
    q_ = __uint_as_float(p1_.x); if (q_ > V) { V = q_; F = p1_.y; }           \
    q_ = __uint_as_float(p1_.z); if (q_ > V) { V = q_; F = p1_.w; }           \
    q_ = __uint_as_float(p2_.x); if (q_ > V) { V = q_; F = p2_.y; }           \
    q_ = __uint_as_float(p2_.z); if (q_ > V) { V = q_; F = p2_.w; }           \
    q_ = __uint_as_float(p3_.x); if (q_ > V) { V = q_; F = p3_.y; }           \
    q_ = __uint_as_float(p3_.z); if (q_ > V) { V = q_; F = p3_.w; }           \
  } while (0)

static __device__ inline void load16(const float* __restrict__ bx, int t,
                                     float px[16], float py[16], float pz[16]) {
  const float4* src = (const float4*)(bx + t * 48);
  float4 v0 = src[0], v1 = src[1], v2 = src[2];
  float4 v3 = src[3], v4 = src[4], v5 = src[5];
  float4 v6 = src[6], v7 = src[7], v8 = src[8];
  float4 v9 = src[9], v10 = src[10], v11 = src[11];
  px[ 0]=v0.x; py[ 0]=v0.y; pz[ 0]=v0.z;
  px[ 1]=v0.w; py[ 1]=v1.x; pz[ 1]=v1.y;
  px[ 2]=v1.z; py[ 2]=v1.w; pz[ 2]=v2.x;
  px[ 3]=v2.y; py[ 3]=v2.z; pz[ 3]=v2.w;
  px[ 4]=v3.x; py[ 4]=v3.y; pz[ 4]=v3.z;
  px[ 5]=v3.w; py[ 5]=v4.x; pz[ 5]=v4.y;
  px[ 6]=v4.z; py[ 6]=v4.w; pz[ 6]=v5.x;
  px[ 7]=v5.y; py[ 7]=v5.z; pz[ 7]=v5.w;
  px[ 8]=v6.x; py[ 8]=v6.y; pz[ 8]=v6.z;
  px[ 9]=v6.w; py[ 9]=v7.x; pz[ 9]=v7.y;
  px[10]=v7.z; py[10]=v7.w; pz[10]=v8.x;
  px[11]=v8.y; py[11]=v8.z; pz[11]=v8.w;
  px[12]=v9.x; py[12]=v9.y; pz[12]=v9.z;
  px[13]=v9.w; py[13]=v10.x; pz[13]=v10.y;
  px[14]=v10.z; py[14]=v10.w; pz[14]=v11.x;
  px[15]=v11.y; py[15]=v11.z; pz[15]=v11.w;
}

// ---------------------------------------------------------------------------
// Kernel 1: farthest point sampling — R12 config (empirical optimum, 821us).
// R11-R13 post-mortems: wall pinned at ~1900-2000 cy/iter across 3 structural
// variants; every removed issue-cycle becomes idle (serial chain ~1400cy).
// 512thr x 16pts packed + LDS point table is the floor. DO NOT TINKER.
//   d = fma(dz,dz, fma(dy,dy, dx*dx))          (bit-exact, DO NOT TOUCH)
// argmax ties -> lowest index.
// ---------------------------------------------------------------------------
__global__
__attribute__((amdgpu_flat_work_group_size(512, 512)))
__attribute__((amdgpu_waves_per_eu(2, 2)))
void fps_kernel(
    const float* __restrict__ xyz, float* __restrict__ out_sampled)
{
  #pragma clang fp contract(off)
  const int b = blockIdx.x;
  const int t = threadIdx.x;
  const float* bx = xyz + (size_t)b * N_PTS * 3;

  float px[16], py[16], pz[16];
  load16(bx, t, px, py, pz);

  f32x2 px2[8], py2[8], pz2[8], ds2[8];
  #pragma unroll
  for (int j = 0; j < 8; ++j) {
    px2[j] = (f32x2){px[2*j], px[2*j+1]};
    py2[j] = (f32x2){py[2*j], py[2*j+1]};
    pz2[j] = (f32x2){pz[2*j], pz[2*j+1]};
    ds2[j] = (f32x2){10000000000.0f, 10000000000.0f};
  }

  __shared__ float lds_p[N_PTS * 3];    // full point table (96 KB): centroid
  __shared__ float out_lds[NSAMP * 3];  // centroids, flushed at end
  __shared__ __align__(16) uint2 part[2][8];  // ping-pong (value bits, index)

  // one-time coalesced stage of the point table (visible at first barrier)
  for (int i = t; i < N_PTS * 3; i += 512) lds_p[i] = bx[i];

  const int lane = t & 63;
  const int wv   = t >> 6;

  float cx = bx[0], cy = bx[1], cz = bx[2];  // initial centroid = point 0

  for (int it = 0; it < NSAMP; ++it) {
    if (t == 0) {
      out_lds[it * 3 + 0] = cx;
      out_lds[it * 3 + 1] = cy;
      out_lds[it * 3 + 2] = cz;
    }

    const f32x2 c2x = (f32x2){cx, cx};
    const f32x2 c2y = (f32x2){cy, cy};
    const f32x2 c2z = (f32x2){cz, cz};
    f32x2 bv2 = (f32x2){-1.0f, -1.0f};
    #pragma unroll
    for (int j = 0; j < 8; ++j) {
      f32x2 dx = px2[j] - c2x;
      f32x2 dy = py2[j] - c2y;
      f32x2 dz = pz2[j] - c2z;
      f32x2 d  = __builtin_elementwise_fma(
          dz, dz, __builtin_elementwise_fma(dy, dy, dx * dx));  // scan-fused
      f32x2 nd = __builtin_elementwise_min(ds2[j], d);
      ds2[j] = nd;
      bv2 = __builtin_elementwise_max(bv2, nd);
    }
    float bv = fmaxf(bv2.x, bv2.y);   // min/max reassociation is exact

    int bi = t * 16 + 15;
    #pragma unroll
    for (int r = 14; r >= 0; --r) {
      float dr = (r & 1) ? ds2[r >> 1].y : ds2[r >> 1].x;
      bi = (dr == bv) ? (t * 16 + r) : bi;
    }

    float rmax = bv;
    DPP_MAXSTEP(rmax, 0x111);  // row_shr:1
    DPP_MAXSTEP(rmax, 0x112);  // row_shr:2
    DPP_MAXSTEP(rmax, 0x114);  // row_shr:4
    DPP_MAXSTEP(rmax, 0x118);  // row_shr:8
    DPP_MAXSTEP(rmax, 0x142);  // row_bcast:15
    DPP_MAXSTEP(rmax, 0x143);  // row_bcast:31
    float vmax = __int_as_float(
        __builtin_amdgcn_readlane(__float_as_int(rmax), 63));

    unsigned long long m = __ballot(bv == vmax);
    int L = __ffsll((long long)m) - 1;
    int widx = __builtin_amdgcn_readlane(bi, L);

    const int slot = it & 1;
    if (lane == 0) part[slot][wv] = make_uint2(__float_as_uint(vmax), (unsigned)widx);
    __syncthreads();   // the ONLY barrier; ping-pong makes it WAR-safe

    float v; unsigned f;
    FINAL8(part[slot], v, f);

    cx = lds_p[f * 3 + 0];   // broadcast ds_read (beats global L2 ~200cy)
    cy = lds_p[f * 3 + 1];
    cz = lds_p[f * 3 + 2];
  }

  __syncthreads();
  float* ob = out_sampled + (size_t)b * NSAMP * 3;
  for (int i = t; i < NSAMP * 3; i += 512) ob[i] = out_lds[i];
}

// ---------------------------------------------------------------------------
// Kernel 2: query_ball_point — unchanged (bit-exact, DO NOT TOUCH).
// ---------------------------------------------------------------------------
__global__ __launch_bounds__(256) void ball_kernel(
    const float* __restrict__ xyz, const float* __restrict__ sampled,
    int* __restrict__ gidx)
{
  #pragma clang fp contract(off)
  const float R2 = (float)(0.2 * 0.2);
  int gt = blockIdx.x * 256 + threadIdx.x;
  int w = gt >> 6;
  int lane = gt & 63;
  const int b = w >> 10;
  const float* cp = sampled + (size_t)w * 3;
  float cx = cp[0], cy = cp[1], cz = cp[2];
  float na = ((cx * cx) + (cy * cy)) + (cz * cz);   // eager: plain adds
  const float* bx = xyz + (size_t)b * N_PTS * 3;
  int* out = gidx + (size_t)w * NGRP;

  int cnt = 0;
  int first = 0;
  for (int base = 0; base < N_PTS && cnt < NGRP; base += 64) {
    int p = base + lane;
    float x = bx[p * 3 + 0];
    float y = bx[p * 3 + 1];
    float z = bx[p * 3 + 2];
    float nb  = ((x * x) + (y * y)) + (z * z);      // eager: plain adds
    float dot = fmaf(cz, z, fmaf(cy, y, cx * x));   // Eigen fma chain
    float sq  = (na + nb) - (2.0f * dot);
    bool inr = !(sq > R2);
    unsigned long long m = __ballot(inr);
    if (cnt == 0 && m != 0ull) first = base + (__ffsll(m) - 1);
    int before = __popcll(m & ((1ull << lane) - 1ull));
    int pos = cnt + before;
    if (inr && pos < NGRP) out[pos] = p;
    cnt += __popcll(m);
  }
  if (cnt < NGRP) {
    int q = cnt + lane;
    if (q < NGRP) out[q] = first;
  }
}

// ---------------------------------------------------------------------------
// Kernel 2.5: weight prep — pack W1/W2/W3 into fragment-ordered bf16 records.
// Record (nt, ks) holds the B-fragment for one 16-col tile / one K-step:
//   record[lane][j] = W[k = 32ks + (lane>>4)*8 + j][n = 16nt + (lane&15)]
// (zero-padded k >= K). 1KB/record, lane*16B consecutive -> coalesced loads.
// Layers: L1 4nt x 3ks = 12 recs, L2 8x2 = 16, L3 16x4 = 64. Total 92KB.
// L1 uses PERMUTED feature order (fea at k'=0..63, rel at k'=64..66,
// pad 67..95); W1 rows permuted to match (k'<64 -> row k'+3; 64..66 -> k'-64).
// ---------------------------------------------------------------------------
__global__ __launch_bounds__(256) void prep_w_kernel(
    const float* __restrict__ W1, const float* __restrict__ W2,
    const float* __restrict__ W3, unsigned short* __restrict__ wf1,
    unsigned short* __restrict__ wf2, unsigned short* __restrict__ wf3)
{
  int tid = blockIdx.x * 256 + threadIdx.x;
  int rec = tid >> 6, lane = tid & 63;
  if (rec >= 92) return;
  const float* W; unsigned short* dst; int N, K, ksteps, rl; int permuted;
  if (rec < 12)      { W = W1; dst = wf1; N = 64;  K = 67;  ksteps = 3; rl = rec;     permuted = 1; }
  else if (rec < 28) { W = W2; dst = wf2; N = 128; K = 64;  ksteps = 2; rl = rec - 12; permuted = 0; }
  else               { W = W3; dst = wf3; N = 256; K = 128; ksteps = 4; rl = rec - 28; permuted = 0; }
  int nt = rl / ksteps, ks = rl - nt * ksteps;
  int n  = nt * 16 + (lane & 15);
  int kb = ks * 32 + (lane >> 4) * 8;
  unsigned short v[8] __attribute__((aligned(16)));
  #pragma unroll
  for (int j = 0; j < 8; ++j) {
    int k = kb + j;
    float val;
    if (permuted) {
      if (k < 64)      val = W[(k + 3) * N + n];   // fea weight rows
      else if (k < K)  val = W[(k - 64) * N + n];  // rel weight rows (k=64..66)
      else             val = 0.0f;
    } else {
      val = (k < K) ? W[k * N + n] : 0.0f;
    }
    v[j] = f2bf(val);
  }
  *(uint4*)(dst + ((size_t)rl * 64 + lane) * 8) = *(const uint4*)v;
}

// ---------------------------------------------------------------------------
// Kernel 3: gather + MLP via bf16 MFMA (fp32 accumulate) + max-pool.
// R15: TWO centroids per block (M=64 rows), 8192 blocks.
//  - nt-major wave tiling: each B-frag loaded once, reused across 4 m-tiles
//    (weight L2 traffic per output /4).
//  - pool via register tree + __shfl_xor(16/32): pmax LDS + barrier removed.
//  - chunked XCD swizzle (bijective, 8192%8==0): each batch's blocks land on
//    ~1 XCD -> 2MB fea per batch fits the 4MB XCD L2.
// Per-tile MFMA accumulation order identical to R14 (same ks order, same bias
// seed); max-pool exact -> mlp output bit-identical to R14.
// Frag layouts (gfx950, HW-verified per guide):
//   A[m=lane&15][k=(lane>>4)*8+j]   B[n=lane&15][k=(lane>>4)*8+j]
//   C/D: col=lane&15, row=(lane>>4)*4+reg
// ---------------------------------------------------------------------------
__global__ __launch_bounds__(256, 4) void mlp_mfma_kernel(
    const float* __restrict__ xyz, const float* __restrict__ fea,
    const float* __restrict__ sampled, const int* __restrict__ gidx,
    const unsigned short* __restrict__ wf1, const unsigned short* __restrict__ wf2,
    const unsigned short* __restrict__ wf3, const float* __restrict__ b1,
    const float* __restrict__ b2, const float* __restrict__ b3,
    float* __restrict__ out)
{
  __shared__ __align__(16) unsigned short fT[64][104];  // feats bf16, K=96 pad
  __shared__ __align__(16) unsigned short h1[64][72];   // K=64 (+8 bank pad)
  __shared__ __align__(16) unsigned short h2[64][136];  // K=128 (+8 bank pad)
  __shared__ int   sidx[64];
  __shared__ float sc[8];

  // chunked XCD swizzle: 8192 blocks -> 1024 consecutive work items per XCD
  const int wk  = (blockIdx.x & 7) * 1024 + (blockIdx.x >> 3);
  const int bs0 = wk * 2;            // first of two centroids (same batch)
  const int b   = bs0 >> 10;
  const int t   = threadIdx.x;
  const int w    = t >> 6;
  const int lane = t & 63;
  const int quad = lane >> 4;
  const int ncol = lane & 15;

  if (t < 64) sidx[t] = gidx[(size_t)bs0 * 32 + t];
  if (t < 6)  sc[t] = sampled[(size_t)bs0 * 3 + t];
  __syncthreads();

  // gather (permuted layout): fea -> cols 0..63 via 4 coalesced float4 loads
  // per thread (4 threads per point); rel -> cols 64..66; zeros 67..95.
  {
    const int pt = t >> 2, c0 = t & 3;
    const int p = sidx[pt];
    const float4* fp4 = (const float4*)(fea + ((size_t)b * N_PTS + p) * 64);
    #pragma unroll
    for (int j = 0; j < 4; ++j) {
      float4 fv = fp4[c0 + 4 * j];
      unsigned short s4[4] __attribute__((aligned(8)));
      s4[0] = f2bf(fv.x); s4[1] = f2bf(fv.y);
      s4[2] = f2bf(fv.z); s4[3] = f2bf(fv.w);
      *(uint2*)&fT[pt][(c0 + 4 * j) * 4] = *(const uint2*)s4;
    }
    if (c0 == 0) {
      const float* xp = xyz + ((size_t)b * N_PTS + p) * 3;
      const int cc = (pt >> 5) * 3;
      unsigned short sr[4] __attribute__((aligned(8)));
      sr[0] = f2bf(xp[0] - sc[cc + 0]);
      sr[1] = f2bf(xp[1] - sc[cc + 1]);
      sr[2] = f2bf(xp[2] - sc[cc + 2]);
      sr[3] = 0;
      *(uint2*)&fT[pt][64] = *(const uint2*)sr;
      *(uint2*)&fT[pt][68] = (uint2){0u, 0u};
    } else {
      // zeros: c0=1 -> 72..79, c0=2 -> 80..87, c0=3 -> 88..95
      *(uint4*)&fT[pt][72 + (c0 - 1) * 8] = (uint4){0u, 0u, 0u, 0u};
    }
  }
  __syncthreads();

  // layer 1: out [64 x 64]. wave w owns nt=w; B loaded once per ks, reused
  // across 4 m-tiles. K: 3 steps.
  {
    const int nt = w;
    float bb = b1[nt * 16 + ncol];
    f32x4 acc[4];
    #pragma unroll
    for (int mt = 0; mt < 4; ++mt) acc[mt] = (f32x4){bb, bb, bb, bb};
    #pragma unroll
    for (int ks = 0; ks < 3; ++ks) {
      bf16x8 bf = *(const bf16x8*)(wf1 + ((size_t)(nt * 3 + ks) * 64 + lane) * 8);
      #pragma unroll
      for (int mt = 0; mt < 4; ++mt) {
        bf16x8 a = *(const bf16x8*)&fT[mt * 16 + ncol][ks * 32 + quad * 8];
        acc[mt] = __builtin_amdgcn_mfma_f32_16x16x32_bf16(a, bf, acc[mt], 0, 0, 0);
      }
    }
    #pragma unroll
    for (int mt = 0; mt < 4; ++mt)
      #pragma unroll
      for (int r = 0; r < 4; ++r)
        h1[mt * 16 + quad * 4 + r][nt * 16 + ncol] = f2bf(fmaxf(acc[mt][r], 0.0f));
  }
  __syncthreads();

  // layer 2: out [64 x 128]. wave w owns nt in {2w, 2w+1}. K: 2 steps.
  #pragma unroll
  for (int i = 0; i < 2; ++i) {
    const int nt = 2 * w + i;
    float bb = b2[nt * 16 + ncol];
    f32x4 acc[4];
    #pragma unroll
    for (int mt = 0; mt < 4; ++mt) acc[mt] = (f32x4){bb, bb, bb, bb};
    #pragma unroll
    for (int ks = 0; ks < 2; ++ks) {
      bf16x8 bf = *(const bf16x8*)(wf2 + ((size_t)(nt * 2 + ks) * 64 + lane) * 8);
      #pragma unroll
      for (int mt = 0; mt < 4; ++mt) {
        bf16x8 a = *(const bf16x8*)&h1[mt * 16 + ncol][ks * 32 + quad * 8];
        acc[mt] = __builtin_amdgcn_mfma_f32_16x16x32_bf16(a, bf, acc[mt], 0, 0, 0);
      }
    }
    #pragma unroll
    for (int mt = 0; mt < 4; ++mt)
      #pragma unroll
      for (int r = 0; r < 4; ++r)
        h2[mt * 16 + quad * 4 + r][nt * 16 + ncol] = f2bf(fmaxf(acc[mt][r], 0.0f));
  }
  __syncthreads();

  // layer 3 + pool: out [64 x 256]. wave w owns nt in {4w..4w+3}, processed
  // in 2 halves (VGPR cap 128 at waves_per_eu=4). K: 4 steps, ks-outer with
  // hoisted A-frags. Pool: reg tree over (mt,r) + shfl_xor(16/32) over quads.
  #pragma unroll
  for (int half = 0; half < 2; ++half) {
    f32x4 acc[2][4];     // [nt_i][mt]
    #pragma unroll
    for (int i = 0; i < 2; ++i) {
      const int nt = 4 * w + half * 2 + i;
      float bb = b3[nt * 16 + ncol];
      #pragma unroll
      for (int mt = 0; mt < 4; ++mt) acc[i][mt] = (f32x4){bb, bb, bb, bb};
    }
    #pragma unroll
    for (int ks = 0; ks < 4; ++ks) {
      bf16x8 a[4];
      #pragma unroll
      for (int mt = 0; mt < 4; ++mt)
        a[mt] = *(const bf16x8*)&h2[mt * 16 + ncol][ks * 32 + quad * 8];
      #pragma unroll
      for (int i = 0; i < 2; ++i) {
        const int nt = 4 * w + half * 2 + i;
        bf16x8 bf = *(const bf16x8*)(wf3 + ((size_t)(nt * 4 + ks) * 64 + lane) * 8);
        #pragma unroll
        for (int mt = 0; mt < 4; ++mt)
          acc[i][mt] = __builtin_amdgcn_mfma_f32_16x16x32_bf16(a[mt], bf, acc[i][mt], 0, 0, 0);
      }
    }
    #pragma unroll
    for (int i = 0; i < 2; ++i) {
      const int nt = 4 * w + half * 2 + i;
      // centroid 0 = rows 0..31 (mt 0,1); centroid 1 = rows 32..63 (mt 2,3)
      float m0 = fmaxf(fmaxf(acc[i][0][0], acc[i][0][1]),
                       fmaxf(acc[i][0][2], acc[i][0][3]));
      m0 = fmaxf(m0, fmaxf(fmaxf(acc[i][1][0], acc[i][1][1]),
                           fmaxf(acc[i][1][2], acc[i][1][3])));
      float m1 = fmaxf(fmaxf(acc[i][2][0], acc[i][2][1]),
                       fmaxf(acc[i][2][2], acc[i][2][3]));
      m1 = fmaxf(m1, fmaxf(fmaxf(acc[i][3][0], acc[i][3][1]),
                           fmaxf(acc[i][3][2], acc[i][3][3])));
      m0 = fmaxf(m0, __shfl_xor(m0, 16));
      m0 = fmaxf(m0, __shfl_xor(m0, 32));
      m1 = fmaxf(m1, __shfl_xor(m1, 16));
      m1 = fmaxf(m1, __shfl_xor(m1, 32));
      if (quad == 0)
        out[(size_t)bs0 * 256 + nt * 16 + ncol] = fmaxf(m0, 0.0f);
      else if (quad == 1)
        out[(size_t)(bs0 + 1) * 256 + nt * 16 + ncol] = fmaxf(m1, 0.0f);
    }
  }
}

// ---------------------------------------------------------------------------
extern "C" void kernel_launch(void* const* d_in, const int* in_sizes, int n_in,
                              void* d_out, int out_size, void* d_ws, size_t ws_size,
                              hipStream_t stream) {
  const float* xyz = (const float*)d_in[0];
  const float* fea = (const float*)d_in[1];
  const float* W1  = (const float*)d_in[2];
  const float* b1  = (const float*)d_in[3];
  const float* W2  = (const float*)d_in[4];
  const float* b2  = (const float*)d_in[5];
  const float* W3  = (const float*)d_in[6];
  const float* b3  = (const float*)d_in[7];

  float* outp    = (float*)d_out;
  float* sampled = outp;                    // output 0: (16,1024,3)
  float* mlp_out = outp + 16 * 1024 * 3;    // output 1: (16,1024,256)
  int*   gidx    = (int*)d_ws;              // 2 MB
  unsigned short* wf1 = (unsigned short*)((char*)d_ws + (2u << 20));
  unsigned short* wf2 = wf1 + (size_t)12 * 64 * 8;   // 12 KB after wf1
  unsigned short* wf3 = wf2 + (size_t)16 * 64 * 8;   // 16 KB after wf2

  fps_kernel<<<16, 512, 0, stream>>>(xyz, sampled);
  prep_w_kernel<<<23, 256, 0, stream>>>(W1, W2, W3, wf1, wf2, wf3);
  ball_kernel<<<4096, 256, 0, stream>>>(xyz, sampled, gidx);
  mlp_mfma_kernel<<<8192, 256, 0, stream>>>(xyz, fea, sampled, gidx,
                                            wf1, wf2, wf3, b1, b2, b3, mlp_out);
}